// Round 3
// baseline (728.308 us; speedup 1.0000x reference)
//
#include <hip/hip_runtime.h>

typedef _Float16 half8v __attribute__((ext_vector_type(8)));
typedef float    f32x4  __attribute__((ext_vector_type(4)));
typedef unsigned short ushort_t;

// ---------- helpers ----------
__device__ __forceinline__ unsigned short f2h(float f) {
  _Float16 h = (_Float16)f;                  // RNE, native v_cvt_f16_f32
  return __builtin_bit_cast(unsigned short, h);
}
__device__ __forceinline__ unsigned f2h2(float lo, float hi) {
  return (unsigned)f2h(lo) | ((unsigned)f2h(hi) << 16);
}
// np.linspace(1/14, 1-1/14, 14) in f64, cast f32 (endpoint exact, like numpy)
__device__ __forceinline__ float lin14(int i) {
  double s = 1.0 / 14.0, stop = 1.0 - s;
  double step = (stop - s) / 13.0;
  return (float)((i == 13) ? stop : s + i * step);
}
// np.linspace(0, 1, 10)
__device__ __forceinline__ float lin10(int i) {
  double st = 1.0 / 9.0;
  return (float)((i == 9) ? 1.0 : i * st);
}
__device__ __forceinline__ float wave_sum(float v) {
  #pragma unroll
  for (int o = 32; o; o >>= 1) v += __shfl_xor(v, o, 64);
  return v;
}
__device__ __forceinline__ float wave_max(float v) {
  #pragma unroll
  for (int o = 32; o; o >>= 1) v = fmaxf(v, __shfl_xor(v, o, 64));
  return v;
}
__device__ __forceinline__ float blk_sum(float v, float* red) {
  v = wave_sum(v);
  if ((threadIdx.x & 63) == 0) red[threadIdx.x >> 6] = v;
  __syncthreads();
  v = red[0] + red[1] + red[2] + red[3];
  __syncthreads();
  return v;
}
__device__ __forceinline__ float blk_max(float v, float* red) {
  v = wave_max(v);
  if ((threadIdx.x & 63) == 0) red[threadIdx.x >> 6] = v;
  __syncthreads();
  v = fmaxf(fmaxf(red[0], red[1]), fmaxf(red[2], red[3]));
  __syncthreads();
  return v;
}

// ---------- K_F: F[100][196], pos, mus (constants) ----------
__global__ void k_F(float* __restrict__ posg, float* __restrict__ musg,
                    float* __restrict__ Fg) {
  int idx = blockIdx.x * 256 + threadIdx.x;
  if (idx < 196) { posg[2*idx] = lin14(idx / 14); posg[2*idx+1] = lin14(idx % 14); }
  if (idx < 100) { musg[2*idx] = lin10(idx / 10); musg[2*idx+1] = lin10(idx % 10); }
  if (idx < 19600) {
    int k = idx / 196, l = idx % 196;
    float mx = lin10(k / 10), my = lin10(k % 10);
    float px = lin14(l / 14), py = lin14(l % 14);
    double dx = (double)mx - (double)px, dy = (double)my - (double)py;
    double d2 = dx * dx + dy * dy;
    Fg[idx] = (float)(exp(-500.0 * d2) / (6.283185307179586 * 0.001));
  }
}

// ---------- K_A: A = F F^T + 0.5 I (f64) ----------
__global__ void k_A(const float* __restrict__ Fg, double* __restrict__ A) {
  int i = blockIdx.x, j = threadIdx.x;
  if (j < 100) {
    const float* Fi = Fg + i * 196;
    const float* Fj = Fg + j * 196;
    double s = 0.0;
    for (int l = 0; l < 196; ++l) s += (double)Fi[l] * (double)Fj[l];
    if (i == j) s += 0.5;
    A[i * 100 + j] = s;
  }
}

// ---------- K_inv: in-place Gauss-Jordan inverse, f64, SPD (no pivoting) ----------
// 2 barriers/iter; div/mod hoisted (rule #20: unrolled, compile-time indexing).
__global__ __launch_bounds__(512) void k_inv(const double* __restrict__ Ag,
                                             double* __restrict__ Ainv) {
  __shared__ double A[100][100];   // 80 KB LDS
  __shared__ double rk[100], ck[100];
  int tid = threadIdx.x;
  int ii[20], jj[20];
  #pragma unroll
  for (int r = 0; r < 20; ++r) {
    int idx = r * 512 + tid;
    ii[r] = idx / 100; jj[r] = idx - ii[r] * 100;
  }
  #pragma unroll
  for (int r = 0; r < 20; ++r) {
    int idx = r * 512 + tid;
    if (idx < 10000) A[ii[r]][jj[r]] = Ag[idx];
  }
  __syncthreads();
  for (int k = 0; k < 100; ++k) {
    if (tid < 100) {
      double pinv = 1.0 / A[k][k];
      rk[tid] = (tid == k) ? pinv : A[k][tid] * pinv;  // scaled pivot row
      ck[tid] = (tid == k) ? 0.0  : A[tid][k];         // original pivot col
    }
    __syncthreads();
    #pragma unroll
    for (int r = 0; r < 20; ++r) {
      int idx = r * 512 + tid;
      if (idx < 10000) {
        int i = ii[r], j = jj[r];
        double v;
        if (i == k)      v = rk[j];
        else if (j == k) v = -ck[i] * rk[k];
        else             v = fma(-ck[i], rk[j], A[i][j]);
        A[i][j] = v;
      }
    }
    __syncthreads();
  }
  #pragma unroll
  for (int r = 0; r < 20; ++r) {
    int idx = r * 512 + tid;
    if (idx < 10000) Ainv[idx] = A[ii[r]][jj[r]];
  }
}

// ---------- K_G: G = F^T @ Ainv  (196 x 100, f64 accumulate) ----------
__global__ void k_G(const float* __restrict__ Fg, const double* __restrict__ Ainv,
                    float* __restrict__ G) {
  int l = blockIdx.x, n = threadIdx.x;
  if (n < 100) {
    double s = 0.0;
    for (int k = 0; k < 100; ++k) s += (double)Fg[k * 196 + l] * Ainv[k * 100 + n];
    G[l * 100 + n] = (float)s;
  }
}

// ---------- K_splitw1: W1[1024][512] f32 -> W1t[512][1024] fp16 (transposed) ----------
__global__ void k_splitw1(const float* __restrict__ W1, ushort_t* __restrict__ W1t) {
  __shared__ float t[32][33];
  int n0 = blockIdx.x * 32, k0 = blockIdx.y * 32;
  int tx = threadIdx.x, ty = threadIdx.y;   // 32 x 8
  #pragma unroll
  for (int i = 0; i < 32; i += 8)
    t[ty + i][tx] = W1[(size_t)(k0 + ty + i) * 512 + n0 + tx];
  __syncthreads();
  #pragma unroll
  for (int i = 0; i < 32; i += 8)
    W1t[(size_t)(n0 + ty + i) * 1024 + k0 + tx] = f2h(t[tx][ty + i]);
}

// ---------- K_wmT: Wm[1024][2048] f32 -> WmT[2048][1024] fp16 (transposed) ----------
__global__ void k_wmT(const float* __restrict__ Wm, ushort_t* __restrict__ WmT) {
  __shared__ float t[32][33];
  int n0 = blockIdx.x * 32, k0 = blockIdx.y * 32;
  int tx = threadIdx.x, ty = threadIdx.y;   // 32 x 8
  #pragma unroll
  for (int i = 0; i < 32; i += 8)
    t[ty + i][tx] = Wm[(size_t)(k0 + ty + i) * 2048 + n0 + tx];
  __syncthreads();
  #pragma unroll
  for (int i = 0; i < 32; i += 8)
    WmT[(size_t)(n0 + ty + i) * 1024 + k0 + tx] = f2h(t[tx][ty + i]);
}

// ---------- K_gemm1: logits = relu(x@W1 + b1) @ W2 (fused epilogue, atomic) ----------
// 128x128 tile, BK=32, 4 waves (2x2), fp16 MFMA 16x16x32, reg-staged LDS (pad 40),
// single-barrier double buffer, XCD swizzle (1568 = 8*196).
__global__ __launch_bounds__(256, 2) void k_gemm1(
    const float* __restrict__ x, const ushort_t* __restrict__ W1t,
    const float* __restrict__ b1, const float* __restrict__ W2,
    float* __restrict__ logits) {
  __shared__ __align__(16) ushort_t As[2][128 * 40];
  __shared__ __align__(16) ushort_t Bs[2][128 * 40];

  int bid  = blockIdx.x;
  int bid2 = (bid & 7) * 196 + (bid >> 3);       // XCD-contiguous chunks
  int tm = bid2 >> 2, tn = bid2 & 3;
  size_t row0 = (size_t)tm * 128;
  int n0 = tn * 128;
  int tid = threadIdx.x, lane = tid & 63;
  int wid = tid >> 6, wm = wid >> 1, wn = wid & 1;

  int srow = tid >> 1, sh = (tid & 1) << 4;      // stage: 128 rows x 2 halves of 16
  const float*    xp = x   + (row0 + srow) * 1024 + sh;
  const ushort_t* wp = W1t + (size_t)(n0 + srow) * 1024 + sh;
  int so = srow * 40 + sh;

  int aro = (wm * 64 + (lane & 15)) * 40 + ((lane >> 4) << 3);
  int bro = (wn * 64 + (lane & 15)) * 40 + ((lane >> 4) << 3);

  f32x4 acc[4][4] = {};
  float4 a4[4]; uint4 b4[2];

  #pragma unroll
  for (int j = 0; j < 4; ++j) a4[j] = *(const float4*)(xp + j * 4);
  b4[0] = *(const uint4*)wp; b4[1] = *(const uint4*)(wp + 8);
  {
    uint4 w0, w1;
    w0.x = f2h2(a4[0].x, a4[0].y); w0.y = f2h2(a4[0].z, a4[0].w);
    w0.z = f2h2(a4[1].x, a4[1].y); w0.w = f2h2(a4[1].z, a4[1].w);
    w1.x = f2h2(a4[2].x, a4[2].y); w1.y = f2h2(a4[2].z, a4[2].w);
    w1.z = f2h2(a4[3].x, a4[3].y); w1.w = f2h2(a4[3].z, a4[3].w);
    *(uint4*)&As[0][so] = w0; *(uint4*)&As[0][so + 8] = w1;
    *(uint4*)&Bs[0][so] = b4[0]; *(uint4*)&Bs[0][so + 8] = b4[1];
  }
  __syncthreads();

  int cur = 0;
  for (int ks = 0; ks < 32; ++ks) {
    if (ks < 31) {  // prefetch next K-slab into regs (hides under MFMA)
      const float* xn = xp + (ks + 1) * 32;
      #pragma unroll
      for (int j = 0; j < 4; ++j) a4[j] = *(const float4*)(xn + j * 4);
      const ushort_t* wn2 = wp + (ks + 1) * 32;
      b4[0] = *(const uint4*)wn2; b4[1] = *(const uint4*)(wn2 + 8);
    }
    half8v af[4], bf[4];
    #pragma unroll
    for (int i = 0; i < 4; ++i) af[i] = *(const half8v*)&As[cur][aro + i * 16 * 40];
    #pragma unroll
    for (int i = 0; i < 4; ++i) bf[i] = *(const half8v*)&Bs[cur][bro + i * 16 * 40];
    #pragma unroll
    for (int i = 0; i < 4; ++i)
      #pragma unroll
      for (int j = 0; j < 4; ++j)
        acc[i][j] = __builtin_amdgcn_mfma_f32_16x16x32_f16(af[i], bf[j], acc[i][j], 0, 0, 0);
    if (ks < 31) {
      uint4 w0, w1;
      w0.x = f2h2(a4[0].x, a4[0].y); w0.y = f2h2(a4[0].z, a4[0].w);
      w0.z = f2h2(a4[1].x, a4[1].y); w0.w = f2h2(a4[1].z, a4[1].w);
      w1.x = f2h2(a4[2].x, a4[2].y); w1.y = f2h2(a4[2].z, a4[2].w);
      w1.z = f2h2(a4[3].x, a4[3].y); w1.w = f2h2(a4[3].z, a4[3].w);
      *(uint4*)&As[cur ^ 1][so] = w0; *(uint4*)&As[cur ^ 1][so + 8] = w1;
      *(uint4*)&Bs[cur ^ 1][so] = b4[0]; *(uint4*)&Bs[cur ^ 1][so + 8] = b4[1];
    }
    __syncthreads();   // one barrier per K-step is sufficient (disjoint buffers)
    cur ^= 1;
  }

  // fused epilogue: logits partial = sum_n relu(acc + b1[n]) * W2[n]
  int cbase = n0 + wn * 64 + (lane & 15);
  float b1v[4], w2v[4];
  #pragma unroll
  for (int j = 0; j < 4; ++j) { b1v[j] = b1[cbase + j * 16]; w2v[j] = W2[cbase + j * 16]; }
  float part[4][4];
  #pragma unroll
  for (int i = 0; i < 4; ++i)
    #pragma unroll
    for (int q = 0; q < 4; ++q) {
      float s = 0.f;
      #pragma unroll
      for (int j = 0; j < 4; ++j) {
        float h = acc[i][j][q] + b1v[j];
        s += fmaxf(h, 0.f) * w2v[j];
      }
      part[i][q] = s;
    }
  #pragma unroll
  for (int off = 1; off < 16; off <<= 1)
    #pragma unroll
    for (int i = 0; i < 4; ++i)
      #pragma unroll
      for (int q = 0; q < 4; ++q)
        part[i][q] += __shfl_xor(part[i][q], off, 64);
  if ((lane & 15) == 0) {
    int rbase = (int)row0 + wm * 64 + ((lane >> 4) << 2);
    #pragma unroll
    for (int i = 0; i < 4; ++i)
      #pragma unroll
      for (int q = 0; q < 4; ++q)
        atomicAdd(&logits[rbase + i * 16 + q], part[i][q]);
  }
}

// ---------- K_batch: softmax, mu, Sigma, Sinv, r, g = G@r   (one block per b) ----------
__global__ __launch_bounds__(256) void k_batch(
    const float* __restrict__ logits, const unsigned char* __restrict__ mask,
    const float* __restrict__ b2, const float* __restrict__ pos,
    const float* __restrict__ mus, const float* __restrict__ G,
    float* __restrict__ g_out) {
  __shared__ float red[4];
  __shared__ float rsh[100];
  int b = blockIdx.x, tid = threadIdx.x;
  bool act = tid < 196;
  float lg = -1e30f;
  if (act) {
    lg = logits[b * 196 + tid] + b2[0];
    if (mask[b * 196 + tid]) lg = -1e9f;
  }
  float m = blk_max(lg, red);
  float e = act ? expf(lg - m) : 0.f;
  float Z = blk_sum(e, red);
  float pv = e / Z;
  float px = act ? pos[2 * tid] : 0.f, py = act ? pos[2 * tid + 1] : 0.f;
  float mux = blk_sum(pv * px, red);
  float muy = blk_sum(pv * py, red);
  float dx = px - mux, dy = py - muy;
  float sxx = blk_sum(pv * dx * dx, red);
  float sxy = blk_sum(pv * dx * dy, red);
  float syy = blk_sum(pv * dy * dy, red);
  float aa = (sxx + 1e-6f) + 1e-3f;
  float bb = sxy;
  float dd = (syy + 1e-6f) + 1e-3f;
  float det = aa * dd - bb * bb;
  float scale = 1.f / (6.2831853071795864f * sqrtf(det));
  if (tid < 100) {
    float dmx = mux - mus[2 * tid], dmy = muy - mus[2 * tid + 1];
    float quad = (dd * dmx * dmx - 2.f * bb * dmx * dmy + aa * dmy * dmy) / det;
    rsh[tid] = expf(-0.5f * quad) * scale;
  }
  __syncthreads();
  if (act) {
    const float* Gr = G + tid * 100;
    float s = 0.f;
    #pragma unroll 4
    for (int n = 0; n < 100; ++n) s = fmaf(Gr[n], rsh[n], s);
    g_out[b * 196 + tid] = s;
  }
}

// ---------- K_ctx: ctxh[b,d] = (fp16) sum_l x[b,l,d] * g[b,l]   (HBM-bound) ----------
__global__ __launch_bounds__(256) void k_ctx(const float* __restrict__ x,
                                             const float* __restrict__ g,
                                             ushort_t* __restrict__ ctxh) {
  int b = blockIdx.y, seg = blockIdx.x, tid = threadIdx.x;
  __shared__ float gs[196];
  if (tid < 196) gs[tid] = g[b * 196 + tid];
  __syncthreads();
  int d = seg * 256 + tid;
  const float* xp = x + (size_t)b * 200704 + d;
  float acc = 0.f;
  #pragma unroll 8
  for (int l = 0; l < 196; ++l) acc = fmaf(xp[(size_t)l * 1024], gs[l], acc);
  ctxh[b * 1024 + d] = f2h(acc);
}

// ---------- K_out2: out = ctxh @ WmT^T + bm   (fp16 MFMA, 64x128 tile, BK=32) ----------
__global__ __launch_bounds__(256, 2) void k_out2(
    const ushort_t* __restrict__ ctxh, const ushort_t* __restrict__ WmT,
    const float* __restrict__ bm, float* __restrict__ out) {
  __shared__ __align__(16) ushort_t As[2][64 * 40];
  __shared__ __align__(16) ushort_t Bs[2][128 * 40];
  int n0 = blockIdx.x * 128;
  int m0 = blockIdx.y * 64;
  int tid = threadIdx.x, lane = tid & 63;
  int wid = tid >> 6, wm = wid >> 1, wn = wid & 1;

  int arow = tid >> 2, aseg = (tid & 3) << 3;          // 64 rows x 4 segs of 8
  const ushort_t* ap = ctxh + (m0 + arow) * 1024 + aseg;
  int aso = arow * 40 + aseg;
  int brow = tid >> 1, bsh = (tid & 1) << 4;           // 128 rows x 2 halves of 16
  const ushort_t* bp = WmT + (size_t)(n0 + brow) * 1024 + bsh;
  int bso = brow * 40 + bsh;

  int aro = (wm * 32 + (lane & 15)) * 40 + ((lane >> 4) << 3);
  int bro = (wn * 64 + (lane & 15)) * 40 + ((lane >> 4) << 3);

  f32x4 acc[2][4] = {};
  uint4 a4, b4[2];
  a4 = *(const uint4*)ap;
  b4[0] = *(const uint4*)bp; b4[1] = *(const uint4*)(bp + 8);
  *(uint4*)&As[0][aso] = a4;
  *(uint4*)&Bs[0][bso] = b4[0]; *(uint4*)&Bs[0][bso + 8] = b4[1];
  __syncthreads();

  int cur = 0;
  for (int ks = 0; ks < 32; ++ks) {
    if (ks < 31) {
      a4 = *(const uint4*)(ap + (ks + 1) * 32);
      b4[0] = *(const uint4*)(bp + (ks + 1) * 32);
      b4[1] = *(const uint4*)(bp + (ks + 1) * 32 + 8);
    }
    half8v af[2], bf[4];
    #pragma unroll
    for (int i = 0; i < 2; ++i) af[i] = *(const half8v*)&As[cur][aro + i * 16 * 40];
    #pragma unroll
    for (int j = 0; j < 4; ++j) bf[j] = *(const half8v*)&Bs[cur][bro + j * 16 * 40];
    #pragma unroll
    for (int i = 0; i < 2; ++i)
      #pragma unroll
      for (int j = 0; j < 4; ++j)
        acc[i][j] = __builtin_amdgcn_mfma_f32_16x16x32_f16(af[i], bf[j], acc[i][j], 0, 0, 0);
    if (ks < 31) {
      *(uint4*)&As[cur ^ 1][aso] = a4;
      *(uint4*)&Bs[cur ^ 1][bso] = b4[0]; *(uint4*)&Bs[cur ^ 1][bso + 8] = b4[1];
    }
    __syncthreads();
    cur ^= 1;
  }

  int rbase = m0 + wm * 32 + ((lane >> 4) << 2);
  int cbase = n0 + wn * 64 + (lane & 15);
  #pragma unroll
  for (int j = 0; j < 4; ++j) {
    float bmv = bm[cbase + j * 16];
    #pragma unroll
    for (int i = 0; i < 2; ++i)
      #pragma unroll
      for (int q = 0; q < 4; ++q)
        out[(size_t)(rbase + i * 16 + q) * 2048 + cbase + j * 16] = acc[i][j][q] + bmv;
  }
}

// ---------- launch ----------
extern "C" void kernel_launch(void* const* d_in, const int* in_sizes, int n_in,
                              void* d_out, int out_size, void* d_ws, size_t ws_size,
                              hipStream_t stream) {
  const float* x  = (const float*)d_in[0];
  const unsigned char* xmask = (const unsigned char*)d_in[1];
  const float* W1 = (const float*)d_in[2];
  const float* b1 = (const float*)d_in[3];
  const float* W2 = (const float*)d_in[4];
  const float* b2 = (const float*)d_in[5];
  const float* Wm = (const float*)d_in[6];
  const float* bm = (const float*)d_in[7];
  float* out = (float*)d_out;

  char* ws = (char*)d_ws;
  float*    Fg     = (float*)(ws + 0);          // 78400 B
  double*   Ainv   = (double*)(ws + 78400);     // 80000 B
  double*   Atmp   = (double*)(ws + 158400);    // 80000 B
  float*    posg   = (float*)(ws + 238400);     // 1568 B
  float*    musg   = (float*)(ws + 239968);     // 800 B
  float*    G      = (float*)(ws + 240768);     // 78400 B
  float*    logits = (float*)(ws + 319168);     // 200704 B
  float*    gbuf   = (float*)(ws + 519872);     // 200704 B
  ushort_t* ctxh   = (ushort_t*)(ws + 720576);  // 524288 B
  ushort_t* W1t    = (ushort_t*)(ws + 1244864); // 1048576 B
  ushort_t* WmT    = (ushort_t*)(ws + 2293440); // 4194304 B  (total ~6.2 MB)

  k_F<<<77, 256, 0, stream>>>(posg, musg, Fg);
  k_A<<<100, 128, 0, stream>>>(Fg, Atmp);
  k_inv<<<1, 512, 0, stream>>>(Atmp, Ainv);
  k_G<<<196, 128, 0, stream>>>(Fg, Ainv, G);
  k_splitw1<<<dim3(16, 32), dim3(32, 8), 0, stream>>>(W1, W1t);
  k_wmT<<<dim3(64, 32), dim3(32, 8), 0, stream>>>(Wm, WmT);
  hipMemsetAsync(logits, 0, 200704, stream);
  k_gemm1<<<1568, 256, 0, stream>>>(x, W1t, b1, W2, logits);
  k_batch<<<256, 256, 0, stream>>>(logits, xmask, b2, posg, musg, G, gbuf);
  k_ctx<<<dim3(4, 256), 256, 0, stream>>>(x, gbuf, ctxh);
  k_out2<<<dim3(16, 4), 256, 0, stream>>>(ctxh, WmT, bm, out);
}

// Round 5
// 524.123 us; speedup vs baseline: 1.3896x; 1.3896x over previous
//
#include <hip/hip_runtime.h>

typedef _Float16 half8v __attribute__((ext_vector_type(8)));
typedef float    f32x4  __attribute__((ext_vector_type(4)));
typedef unsigned short ushort_t;

// ---------- helpers ----------
__device__ __forceinline__ unsigned short f2h(float f) {
  _Float16 h = (_Float16)f;                  // RNE, native v_cvt_f16_f32
  return __builtin_bit_cast(unsigned short, h);
}
__device__ __forceinline__ unsigned f2h2(float lo, float hi) {
  return (unsigned)f2h(lo) | ((unsigned)f2h(hi) << 16);
}
// np.linspace(1/14, 1-1/14, 14) in f64, cast f32 (endpoint exact, like numpy)
__device__ __forceinline__ float lin14(int i) {
  double s = 1.0 / 14.0, stop = 1.0 - s;
  double step = (stop - s) / 13.0;
  return (float)((i == 13) ? stop : s + i * step);
}
// np.linspace(0, 1, 10)
__device__ __forceinline__ float lin10(int i) {
  double st = 1.0 / 9.0;
  return (float)((i == 9) ? 1.0 : i * st);
}
__device__ __forceinline__ float wave_sum(float v) {
  #pragma unroll
  for (int o = 32; o; o >>= 1) v += __shfl_xor(v, o, 64);
  return v;
}
__device__ __forceinline__ float wave_max(float v) {
  #pragma unroll
  for (int o = 32; o; o >>= 1) v = fmaxf(v, __shfl_xor(v, o, 64));
  return v;
}
__device__ __forceinline__ float blk_sum(float v, float* red) {
  v = wave_sum(v);
  if ((threadIdx.x & 63) == 0) red[threadIdx.x >> 6] = v;
  __syncthreads();
  v = red[0] + red[1] + red[2] + red[3];
  __syncthreads();
  return v;
}
__device__ __forceinline__ float blk_max(float v, float* red) {
  v = wave_max(v);
  if ((threadIdx.x & 63) == 0) red[threadIdx.x >> 6] = v;
  __syncthreads();
  v = fmaxf(fmaxf(red[0], red[1]), fmaxf(red[2], red[3]));
  __syncthreads();
  return v;
}

// ---------- K_F: F[100][196], pos, mus (constants) ----------
__global__ void k_F(float* __restrict__ posg, float* __restrict__ musg,
                    float* __restrict__ Fg) {
  int idx = blockIdx.x * 256 + threadIdx.x;
  if (idx < 196) { posg[2*idx] = lin14(idx / 14); posg[2*idx+1] = lin14(idx % 14); }
  if (idx < 100) { musg[2*idx] = lin10(idx / 10); musg[2*idx+1] = lin10(idx % 10); }
  if (idx < 19600) {
    int k = idx / 196, l = idx % 196;
    float mx = lin10(k / 10), my = lin10(k % 10);
    float px = lin14(l / 14), py = lin14(l % 14);
    double dx = (double)mx - (double)px, dy = (double)my - (double)py;
    double d2 = dx * dx + dy * dy;
    Fg[idx] = (float)(exp(-500.0 * d2) / (6.283185307179586 * 0.001));
  }
}

// ---------- K_A: A = F F^T + 0.5 I (f64) ----------
__global__ void k_A(const float* __restrict__ Fg, double* __restrict__ A) {
  int i = blockIdx.x, j = threadIdx.x;
  if (j < 100) {
    const float* Fi = Fg + i * 196;
    const float* Fj = Fg + j * 196;
    double s = 0.0;
    for (int l = 0; l < 196; ++l) s += (double)Fi[l] * (double)Fj[l];
    if (i == j) s += 0.5;
    A[i * 100 + j] = s;
  }
}

// ---------- K_inv v3: register-resident Gauss-Jordan, f64, SPD ----------
// Theory (r3 counters: 267us, VALUBusy 0.05% -> pure LDS/barrier latency):
// 500 threads each own a 4x5 register block of A; per iter only 9 broadcast
// LDS reads + 20 f64 FMAs per thread, 2 barriers.  Branch-free rank-1 update
// via rk[k]=1+1/p, ck[k]=p-1 (algebraically exact GJ for all 4 cases:
// pivot p-(p-1)(1+1/p)=1/p; row A[k][j]/p; col -A[i][k]/p; interior).
// Hazard audit: iter k+1's rkv/ckv write is fenced by barrier #1; rowraw
// rewrite only read post-barrier.  Predicted 267 -> ~25-50 us.
__global__ __launch_bounds__(512) void k_inv(const double* __restrict__ Ag,
                                             double* __restrict__ Ainv) {
  __shared__ double rowraw[100], colraw[100], rkv[100], ckv[100];
  int t = threadIdx.x;
  int rb = t / 20, cb = t % 20;          // rb<25: rows [4rb,4rb+4), cols [5cb,5cb+5)
  bool own = t < 500;
  double a[4][5];
  if (own) {
    #pragma unroll
    for (int r = 0; r < 4; ++r)
      #pragma unroll
      for (int c = 0; c < 5; ++c)
        a[r][c] = Ag[(4 * rb + r) * 100 + 5 * cb + c];
  }
  __syncthreads();
  for (int k = 0; k < 100; ++k) {
    int krb = k >> 2, klr = k & 3;
    int kcb = k / 5,  klc = k - 5 * kcb;
    // publish raw pivot row / col
    if (own && rb == krb) {
      #pragma unroll
      for (int r = 0; r < 4; ++r)
        if (r == klr) {
          #pragma unroll
          for (int c = 0; c < 5; ++c) rowraw[5 * cb + c] = a[r][c];
        }
    }
    if (own && cb == kcb) {
      #pragma unroll
      for (int c = 0; c < 5; ++c)
        if (c == klc) {
          #pragma unroll
          for (int r = 0; r < 4; ++r) colraw[4 * rb + r] = a[r][c];
        }
    }
    __syncthreads();
    if (t < 100) {
      double p = rowraw[k], pinv = 1.0 / p;
      rkv[t] = (t == k) ? 1.0 + pinv : rowraw[t] * pinv;
      ckv[t] = (t == k) ? p - 1.0    : colraw[t];
    }
    __syncthreads();
    if (own) {
      double ckl[4], rkl[5];
      #pragma unroll
      for (int r = 0; r < 4; ++r) ckl[r] = ckv[4 * rb + r];
      #pragma unroll
      for (int c = 0; c < 5; ++c) rkl[c] = rkv[5 * cb + c];
      #pragma unroll
      for (int r = 0; r < 4; ++r)
        #pragma unroll
        for (int c = 0; c < 5; ++c)
          a[r][c] = fma(-ckl[r], rkl[c], a[r][c]);
    }
    // no 3rd barrier needed: next publish writes rowraw/colraw, read only
    // after next barrier; update reads rkv/ckv only.
  }
  if (own) {
    #pragma unroll
    for (int r = 0; r < 4; ++r)
      #pragma unroll
      for (int c = 0; c < 5; ++c)
        Ainv[(4 * rb + r) * 100 + 5 * cb + c] = a[r][c];
  }
}

// ---------- K_G: G = F^T @ Ainv  (196 x 100, f64 accumulate) ----------
__global__ void k_G(const float* __restrict__ Fg, const double* __restrict__ Ainv,
                    float* __restrict__ G) {
  int l = blockIdx.x, n = threadIdx.x;
  if (n < 100) {
    double s = 0.0;
    for (int k = 0; k < 100; ++k) s += (double)Fg[k * 196 + l] * Ainv[k * 100 + n];
    G[l * 100 + n] = (float)s;
  }
}

// ---------- K_splitw1: W1[1024][512] f32 -> W1t[512][1024] fp16 (transposed) ----------
__global__ void k_splitw1(const float* __restrict__ W1, ushort_t* __restrict__ W1t) {
  __shared__ float t[32][33];
  int n0 = blockIdx.x * 32, k0 = blockIdx.y * 32;
  int tx = threadIdx.x, ty = threadIdx.y;   // 32 x 8
  #pragma unroll
  for (int i = 0; i < 32; i += 8)
    t[ty + i][tx] = W1[(size_t)(k0 + ty + i) * 512 + n0 + tx];
  __syncthreads();
  #pragma unroll
  for (int i = 0; i < 32; i += 8)
    W1t[(size_t)(n0 + ty + i) * 1024 + k0 + tx] = f2h(t[tx][ty + i]);
}

// ---------- K_wmT: Wm[1024][2048] f32 -> WmT[2048][1024] fp16 (transposed) ----------
__global__ void k_wmT(const float* __restrict__ Wm, ushort_t* __restrict__ WmT) {
  __shared__ float t[32][33];
  int n0 = blockIdx.x * 32, k0 = blockIdx.y * 32;
  int tx = threadIdx.x, ty = threadIdx.y;   // 32 x 8
  #pragma unroll
  for (int i = 0; i < 32; i += 8)
    t[ty + i][tx] = Wm[(size_t)(k0 + ty + i) * 2048 + n0 + tx];
  __syncthreads();
  #pragma unroll
  for (int i = 0; i < 32; i += 8)
    WmT[(size_t)(n0 + ty + i) * 1024 + k0 + tx] = f2h(t[tx][ty + i]);
}

// ---------- K_gemm1: logits = relu(x@W1 + b1) @ W2 (fused epilogue, atomic) ----------
// 128x128 tile, BK=32, 4 waves (2x2), fp16 MFMA 16x16x32, reg-staged LDS (pad 40),
// single-barrier double buffer, XCD swizzle (1568 = 8*196).
// Staging map: x = 8 lanes/row (128B contiguous segments), W1t = 4 lanes/row
// (64B segments) -> ~4x fewer memory transactions than 2-lanes/row.
__global__ __launch_bounds__(256, 2) void k_gemm1(
    const float* __restrict__ x, const ushort_t* __restrict__ W1t,
    const float* __restrict__ b1, const float* __restrict__ W2,
    float* __restrict__ logits) {
  __shared__ __align__(16) ushort_t As[2][128 * 40];
  __shared__ __align__(16) ushort_t Bs[2][128 * 40];

  int bid  = blockIdx.x;
  int bid2 = (bid & 7) * 196 + (bid >> 3);       // XCD-contiguous chunks
  int tm = bid2 >> 2, tn = bid2 & 3;
  size_t row0 = (size_t)tm * 128;
  int n0 = tn * 128;
  int tid = threadIdx.x, lane = tid & 63;
  int wid = tid >> 6, wm = wid >> 1, wn = wid & 1;

  // coalesced stage mapping
  const float*    xp = x   + (row0 + (tid >> 3)) * 1024 + ((tid & 7) << 2);
  const ushort_t* wp = W1t + (size_t)(n0 + (tid >> 2)) * 1024 + ((tid & 3) << 3);
  int so_a = (tid >> 3) * 40 + ((tid & 7) << 2);
  int so_b = (tid >> 2) * 40 + ((tid & 3) << 3);

  int aro = (wm * 64 + (lane & 15)) * 40 + ((lane >> 4) << 3);
  int bro = (wn * 64 + (lane & 15)) * 40 + ((lane >> 4) << 3);

  f32x4 acc[4][4] = {};
  float4 a4[4]; uint4 b4[2];

  #pragma unroll
  for (int r = 0; r < 4; ++r) a4[r] = *(const float4*)(xp + r * 32 * 1024);
  #pragma unroll
  for (int r = 0; r < 2; ++r) b4[r] = *(const uint4*)(wp + r * 64 * 1024);
  #pragma unroll
  for (int r = 0; r < 4; ++r) {
    uint2 w; w.x = f2h2(a4[r].x, a4[r].y); w.y = f2h2(a4[r].z, a4[r].w);
    *(uint2*)&As[0][so_a + r * 32 * 40] = w;
  }
  #pragma unroll
  for (int r = 0; r < 2; ++r) *(uint4*)&Bs[0][so_b + r * 64 * 40] = b4[r];
  __syncthreads();

  int cur = 0;
  for (int ks = 0; ks < 32; ++ks) {
    if (ks < 31) {  // prefetch next K-slab into regs (hides under MFMA)
      #pragma unroll
      for (int r = 0; r < 4; ++r)
        a4[r] = *(const float4*)(xp + (ks + 1) * 32 + r * 32 * 1024);
      #pragma unroll
      for (int r = 0; r < 2; ++r)
        b4[r] = *(const uint4*)(wp + (ks + 1) * 32 + r * 64 * 1024);
    }
    half8v af[4], bf[4];
    #pragma unroll
    for (int i = 0; i < 4; ++i) af[i] = *(const half8v*)&As[cur][aro + i * 16 * 40];
    #pragma unroll
    for (int i = 0; i < 4; ++i) bf[i] = *(const half8v*)&Bs[cur][bro + i * 16 * 40];
    #pragma unroll
    for (int i = 0; i < 4; ++i)
      #pragma unroll
      for (int j = 0; j < 4; ++j)
        acc[i][j] = __builtin_amdgcn_mfma_f32_16x16x32_f16(af[i], bf[j], acc[i][j], 0, 0, 0);
    if (ks < 31) {
      #pragma unroll
      for (int r = 0; r < 4; ++r) {
        uint2 w; w.x = f2h2(a4[r].x, a4[r].y); w.y = f2h2(a4[r].z, a4[r].w);
        *(uint2*)&As[cur ^ 1][so_a + r * 32 * 40] = w;
      }
      #pragma unroll
      for (int r = 0; r < 2; ++r) *(uint4*)&Bs[cur ^ 1][so_b + r * 64 * 40] = b4[r];
    }
    __syncthreads();   // one barrier per K-step is sufficient (disjoint buffers)
    cur ^= 1;
  }

  // fused epilogue: logits partial = sum_n relu(acc + b1[n]) * W2[n]
  int cbase = n0 + wn * 64 + (lane & 15);
  float b1v[4], w2v[4];
  #pragma unroll
  for (int j = 0; j < 4; ++j) { b1v[j] = b1[cbase + j * 16]; w2v[j] = W2[cbase + j * 16]; }
  float part[4][4];
  #pragma unroll
  for (int i = 0; i < 4; ++i)
    #pragma unroll
    for (int q = 0; q < 4; ++q) {
      float s = 0.f;
      #pragma unroll
      for (int j = 0; j < 4; ++j) {
        float h = acc[i][j][q] + b1v[j];
        s += fmaxf(h, 0.f) * w2v[j];
      }
      part[i][q] = s;
    }
  #pragma unroll
  for (int off = 1; off < 16; off <<= 1)
    #pragma unroll
    for (int i = 0; i < 4; ++i)
      #pragma unroll
      for (int q = 0; q < 4; ++q)
        part[i][q] += __shfl_xor(part[i][q], off, 64);
  if ((lane & 15) == 0) {
    int rbase = (int)row0 + wm * 64 + ((lane >> 4) << 2);
    #pragma unroll
    for (int i = 0; i < 4; ++i)
      #pragma unroll
      for (int q = 0; q < 4; ++q)
        atomicAdd(&logits[rbase + i * 16 + q], part[i][q]);
  }
}

// ---------- K_batch: softmax, mu, Sigma, Sinv, r, g = G@r   (one block per b) ----------
__global__ __launch_bounds__(256) void k_batch(
    const float* __restrict__ logits, const unsigned char* __restrict__ mask,
    const float* __restrict__ b2, const float* __restrict__ pos,
    const float* __restrict__ mus, const float* __restrict__ G,
    float* __restrict__ g_out) {
  __shared__ float red[4];
  __shared__ float rsh[100];
  int b = blockIdx.x, tid = threadIdx.x;
  bool act = tid < 196;
  float lg = -1e30f;
  if (act) {
    lg = logits[b * 196 + tid] + b2[0];
    if (mask[b * 196 + tid]) lg = -1e9f;
  }
  float m = blk_max(lg, red);
  float e = act ? expf(lg - m) : 0.f;
  float Z = blk_sum(e, red);
  float pv = e / Z;
  float px = act ? pos[2 * tid] : 0.f, py = act ? pos[2 * tid + 1] : 0.f;
  float mux = blk_sum(pv * px, red);
  float muy = blk_sum(pv * py, red);
  float dx = px - mux, dy = py - muy;
  float sxx = blk_sum(pv * dx * dx, red);
  float sxy = blk_sum(pv * dx * dy, red);
  float syy = blk_sum(pv * dy * dy, red);
  float aa = (sxx + 1e-6f) + 1e-3f;
  float bb = sxy;
  float dd = (syy + 1e-6f) + 1e-3f;
  float det = aa * dd - bb * bb;
  float scale = 1.f / (6.2831853071795864f * sqrtf(det));
  if (tid < 100) {
    float dmx = mux - mus[2 * tid], dmy = muy - mus[2 * tid + 1];
    float quad = (dd * dmx * dmx - 2.f * bb * dmx * dmy + aa * dmy * dmy) / det;
    rsh[tid] = expf(-0.5f * quad) * scale;
  }
  __syncthreads();
  if (act) {
    const float* Gr = G + tid * 100;
    float s = 0.f;
    #pragma unroll 4
    for (int n = 0; n < 100; ++n) s = fmaf(Gr[n], rsh[n], s);
    g_out[b * 196 + tid] = s;
  }
}

// ---------- K_ctx: ctxh[b,d] = (fp16) sum_l x[b,l,d] * g[b,l]   (HBM-bound) ----------
__global__ __launch_bounds__(256) void k_ctx(const float* __restrict__ x,
                                             const float* __restrict__ g,
                                             ushort_t* __restrict__ ctxh) {
  int b = blockIdx.y, seg = blockIdx.x, tid = threadIdx.x;
  __shared__ float gs[196];
  if (tid < 196) gs[tid] = g[b * 196 + tid];
  __syncthreads();
  int d = seg * 256 + tid;
  const float* xp = x + (size_t)b * 200704 + d;
  float acc = 0.f;
  #pragma unroll 8
  for (int l = 0; l < 196; ++l) acc = fmaf(xp[(size_t)l * 1024], gs[l], acc);
  ctxh[b * 1024 + d] = f2h(acc);
}

// ---------- K_out2: out = ctxh @ WmT^T + bm   (fp16 MFMA, 64x128 tile, BK=32) ----------
__global__ __launch_bounds__(256, 2) void k_out2(
    const ushort_t* __restrict__ ctxh, const ushort_t* __restrict__ WmT,
    const float* __restrict__ bm, float* __restrict__ out) {
  __shared__ __align__(16) ushort_t As[2][64 * 40];
  __shared__ __align__(16) ushort_t Bs[2][128 * 40];
  int n0 = blockIdx.x * 128;
  int m0 = blockIdx.y * 64;
  int tid = threadIdx.x, lane = tid & 63;
  int wid = tid >> 6, wm = wid >> 1, wn = wid & 1;

  int arow = tid >> 2, aseg = (tid & 3) << 3;          // 64 rows x 4 segs of 8
  const ushort_t* ap = ctxh + (m0 + arow) * 1024 + aseg;
  int aso = arow * 40 + aseg;
  int brow = tid >> 1, bsh = (tid & 1) << 4;           // 128 rows x 2 halves of 16
  const ushort_t* bp = WmT + (size_t)(n0 + brow) * 1024 + bsh;
  int bso = brow * 40 + bsh;

  int aro = (wm * 32 + (lane & 15)) * 40 + ((lane >> 4) << 3);
  int bro = (wn * 64 + (lane & 15)) * 40 + ((lane >> 4) << 3);

  f32x4 acc[2][4] = {};
  uint4 a4, b4[2];
  a4 = *(const uint4*)ap;
  b4[0] = *(const uint4*)bp; b4[1] = *(const uint4*)(bp + 8);
  *(uint4*)&As[0][aso] = a4;
  *(uint4*)&Bs[0][bso] = b4[0]; *(uint4*)&Bs[0][bso + 8] = b4[1];
  __syncthreads();

  int cur = 0;
  for (int ks = 0; ks < 32; ++ks) {
    if (ks < 31) {
      a4 = *(const uint4*)(ap + (ks + 1) * 32);
      b4[0] = *(const uint4*)(bp + (ks + 1) * 32);
      b4[1] = *(const uint4*)(bp + (ks + 1) * 32 + 8);
    }
    half8v af[2], bf[4];
    #pragma unroll
    for (int i = 0; i < 2; ++i) af[i] = *(const half8v*)&As[cur][aro + i * 16 * 40];
    #pragma unroll
    for (int j = 0; j < 4; ++j) bf[j] = *(const half8v*)&Bs[cur][bro + j * 16 * 40];
    #pragma unroll
    for (int i = 0; i < 2; ++i)
      #pragma unroll
      for (int j = 0; j < 4; ++j)
        acc[i][j] = __builtin_amdgcn_mfma_f32_16x16x32_f16(af[i], bf[j], acc[i][j], 0, 0, 0);
    if (ks < 31) {
      *(uint4*)&As[cur ^ 1][aso] = a4;
      *(uint4*)&Bs[cur ^ 1][bso] = b4[0]; *(uint4*)&Bs[cur ^ 1][bso + 8] = b4[1];
    }
    __syncthreads();
    cur ^= 1;
  }

  int rbase = m0 + wm * 32 + ((lane >> 4) << 2);
  int cbase = n0 + wn * 64 + (lane & 15);
  #pragma unroll
  for (int j = 0; j < 4; ++j) {
    float bmv = bm[cbase + j * 16];
    #pragma unroll
    for (int i = 0; i < 2; ++i)
      #pragma unroll
      for (int q = 0; q < 4; ++q)
        out[(size_t)(rbase + i * 16 + q) * 2048 + cbase + j * 16] = acc[i][j][q] + bmv;
  }
}

// ---------- launch ----------
extern "C" void kernel_launch(void* const* d_in, const int* in_sizes, int n_in,
                              void* d_out, int out_size, void* d_ws, size_t ws_size,
                              hipStream_t stream) {
  const float* x  = (const float*)d_in[0];
  const unsigned char* xmask = (const unsigned char*)d_in[1];
  const float* W1 = (const float*)d_in[2];
  const float* b1 = (const float*)d_in[3];
  const float* W2 = (const float*)d_in[4];
  const float* b2 = (const float*)d_in[5];
  const float* Wm = (const float*)d_in[6];
  const float* bm = (const float*)d_in[7];
  float* out = (float*)d_out;

  char* ws = (char*)d_ws;
  float*    Fg     = (float*)(ws + 0);          // 78400 B
  double*   Ainv   = (double*)(ws + 78400);     // 80000 B
  double*   Atmp   = (double*)(ws + 158400);    // 80000 B
  float*    posg   = (float*)(ws + 238400);     // 1568 B
  float*    musg   = (float*)(ws + 239968);     // 800 B
  float*    G      = (float*)(ws + 240768);     // 78400 B
  float*    logits = (float*)(ws + 319168);     // 200704 B
  float*    gbuf   = (float*)(ws + 519872);     // 200704 B
  ushort_t* ctxh   = (ushort_t*)(ws + 720576);  // 524288 B
  ushort_t* W1t    = (ushort_t*)(ws + 1244864); // 1048576 B
  ushort_t* WmT    = (ushort_t*)(ws + 2293440); // 4194304 B  (total ~6.2 MB)

  k_F<<<77, 256, 0, stream>>>(posg, musg, Fg);
  k_A<<<100, 128, 0, stream>>>(Fg, Atmp);
  k_inv<<<1, 512, 0, stream>>>(Atmp, Ainv);
  k_G<<<196, 128, 0, stream>>>(Fg, Ainv, G);
  k_splitw1<<<dim3(16, 32), dim3(32, 8), 0, stream>>>(W1, W1t);
  k_wmT<<<dim3(64, 32), dim3(32, 8), 0, stream>>>(Wm, WmT);
  hipMemsetAsync(logits, 0, 200704, stream);
  k_gemm1<<<1568, 256, 0, stream>>>(x, W1t, b1, W2, logits);
  k_batch<<<256, 256, 0, stream>>>(logits, xmask, b2, posg, musg, G, gbuf);
  k_ctx<<<dim3(4, 256), 256, 0, stream>>>(x, gbuf, ctxh);
  k_out2<<<dim3(16, 4), 256, 0, stream>>>(ctxh, WmT, bm, out);
}